// Round 5
// baseline (438.114 us; speedup 1.0000x reference)
//
#include <hip/hip_runtime.h>
#include <stdint.h>

typedef unsigned long long u64;
typedef int v4i  __attribute__((ext_vector_type(4)));
typedef int v16i __attribute__((ext_vector_type(16)));

#define N_ 128
#define C_ 256
#define H_ 28
#define W_ 28
#define BN_EPS_ 1e-5f

#define GP_ 30                            // zero-padded grid 30x30
#define MROWS_ (N_ * GP_ * GP_)           // 115200 GEMM rows
#define A_BYTES_ ((size_t)(MROWS_ + 64) * C_)   // + rear slack (shift reads <= +62 rows)
#define B_BYTES_ ((size_t)9 * C_ * C_)

static __device__ inline v16i vzero16() {
    v16i v;
    #pragma unroll
    for (int i = 0; i < 16; ++i) v[i] = 0;
    return v;
}

// ===========================================================================
// MFMA path
// ===========================================================================

// ---------------------------------------------------------------------------
// pack_a: A[n][gy][gx][ci] i8 = sign(x[n,ci,gy-1,gx-1]) in {+1,-1}, zero halo.
// Block=(n,gy). Interior: stage x-slab [256c][28w] via float4 (coalesced),
// then emit ci-fastest sign bytes (256B runs, coalesced dword stores).
// ---------------------------------------------------------------------------
__global__ __launch_bounds__(256) void pack_a_kernel(const float* __restrict__ x,
                                                     char* __restrict__ A) {
    int gy = blockIdx.x % GP_;
    int n  = blockIdx.x / GP_;
    int* arow = (int*)(A + ((size_t)n * GP_ + gy) * GP_ * C_);
    if (gy == 0 || gy == GP_ - 1) {
        for (int i = threadIdx.x; i < GP_ * 64; i += 256) arow[i] = 0;
        return;
    }
    int h = gy - 1;
    __shared__ float sx[C_][W_ + 1];
    const float* xplane = x + ((size_t)n * C_ * H_ + h) * W_;
    for (int i = threadIdx.x; i < C_ * 7; i += 256) {
        int c = i / 7, q = i - c * 7;
        float4 v = *(const float4*)(xplane + (size_t)c * (H_ * W_) + q * 4);
        sx[c][q*4+0] = v.x; sx[c][q*4+1] = v.y;
        sx[c][q*4+2] = v.z; sx[c][q*4+3] = v.w;
    }
    __syncthreads();
    for (int i = threadIdx.x; i < GP_ * 64; i += 256) {
        int gx = i >> 6, d = i & 63;
        unsigned r = 0;
        if (gx > 0 && gx < GP_ - 1) {
            int w = gx - 1;
            unsigned b0 = sx[4*d+0][w] < 0.f ? 0xFFu : 0x01u;
            unsigned b1 = sx[4*d+1][w] < 0.f ? 0xFFu : 0x01u;
            unsigned b2 = sx[4*d+2][w] < 0.f ? 0xFFu : 0x01u;
            unsigned b3 = sx[4*d+3][w] < 0.f ? 0xFFu : 0x01u;
            r = b0 | (b1 << 8) | (b2 << 16) | (b3 << 24);
        }
        arow[i] = (int)r;
    }
}

// ---------------------------------------------------------------------------
// pack_b: B[tap][co][ci] i8 = sign(w[co,ci,tap]), tap = kh*3+kw. Gather reads
// (2.4 MB total, L2), ci-contiguous writes.
// ---------------------------------------------------------------------------
__global__ __launch_bounds__(256) void pack_b_kernel(const float* __restrict__ w,
                                                     char* __restrict__ B) {
    int tap = blockIdx.x % 9;
    int cog = blockIdx.x / 9;
    int co  = cog * 32 + (threadIdx.x >> 3);
    int* brow = (int*)(B + ((size_t)tap * C_ + co) * C_);
    for (int k = 0; k < 8; ++k) {
        int d = (threadIdx.x & 7) + 8 * k;
        unsigned r = 0;
        #pragma unroll
        for (int j = 0; j < 4; ++j) {
            int ci = 4 * d + j;
            float v = w[((size_t)co * C_ + ci) * 9 + tap];
            r |= (v < 0.f ? 0xFFu : 0x01u) << (8 * j);
        }
        brow[d] = (int)r;
    }
}

// ---------------------------------------------------------------------------
// gemm: C[m=(n,Y,X), co] = sum_{tap} A[m + dh*30+dw, :] . B[tap][co][:]
// BM=128, BN=256, 4 waves (wave-tile 64x128, frags 2m x 4n of 32x32x32_i8).
// A/B fragments read straight from global (L2-hot); software ping-pong
// prefetch one k-substep ahead. Epilogue: per-32-row LDS transpose so the
// BN+clip+residual+store phase is lane=m coalesced.
// Valid outputs: Y<28 && X<28 -> out(h=Y, w=X). Rest computed+discarded.
// ---------------------------------------------------------------------------
__global__ __launch_bounds__(256, 2) void gemm_kernel(
    const char* __restrict__ A, const char* __restrict__ B,
    const float* __restrict__ x,
    const float* __restrict__ gamma, const float* __restrict__ beta,
    const float* __restrict__ mean, const float* __restrict__ var,
    float* __restrict__ out) {

    int t   = threadIdx.x;
    int wid = t >> 6, lane = t & 63;
    int wm  = wid & 1, wn = wid >> 1;     // wave grid 2m x 2n
    int l31 = lane & 31, lh = lane >> 5;
    long bm0 = (long)blockIdx.x * 128;

    __shared__ float sE[32][257];

    // BN params per n-frag (co = wn*128 + fn*32 + l31)
    float inv_f[4], bias_f[4];
    #pragma unroll
    for (int fn = 0; fn < 4; ++fn) {
        int co = wn * 128 + fn * 32 + l31;
        float iv = gamma[co] / sqrtf(var[co] + BN_EPS_);
        inv_f[fn]  = iv;
        bias_f[fn] = beta[co] - mean[co] * iv;
    }

    const char* Ab0 = A + (size_t)(bm0 + wm * 64 +  0 + l31) * C_ + lh * 16;
    const char* Ab1 = A + (size_t)(bm0 + wm * 64 + 32 + l31) * C_ + lh * 16;
    const char* Bb0 = B + (size_t)(wn * 128 +   0 + l31) * C_ + lh * 16;
    const char* Bb1 = B + (size_t)(wn * 128 +  32 + l31) * C_ + lh * 16;
    const char* Bb2 = B + (size_t)(wn * 128 +  64 + l31) * C_ + lh * 16;
    const char* Bb3 = B + (size_t)(wn * 128 +  96 + l31) * C_ + lh * 16;

    v16i acc00 = vzero16(), acc01 = vzero16(), acc02 = vzero16(), acc03 = vzero16();
    v16i acc10 = vzero16(), acc11 = vzero16(), acc12 = vzero16(), acc13 = vzero16();

#define LOADK(kk, ra0, ra1, rb0, rb1, rb2, rb3)                                \
    {                                                                          \
        int tap_ = (kk) >> 3, s_ = (kk) & 7;                                   \
        int dh_ = tap_ / 3, dw_ = tap_ - dh_ * 3;                              \
        size_t ao_ = (size_t)(dh_ * GP_ + dw_) * C_ + (size_t)s_ * 32;         \
        size_t bo_ = (size_t)tap_ * C_ * C_ + (size_t)s_ * 32;                 \
        ra0 = *(const v4i*)(Ab0 + ao_);                                        \
        ra1 = *(const v4i*)(Ab1 + ao_);                                        \
        rb0 = *(const v4i*)(Bb0 + bo_);                                        \
        rb1 = *(const v4i*)(Bb1 + bo_);                                        \
        rb2 = *(const v4i*)(Bb2 + bo_);                                        \
        rb3 = *(const v4i*)(Bb3 + bo_);                                        \
    }

#define MFMA8(aa0, aa1, bb0, bb1, bb2, bb3)                                    \
    acc00 = __builtin_amdgcn_mfma_i32_32x32x32_i8(aa0, bb0, acc00, 0, 0, 0);   \
    acc01 = __builtin_amdgcn_mfma_i32_32x32x32_i8(aa0, bb1, acc01, 0, 0, 0);   \
    acc02 = __builtin_amdgcn_mfma_i32_32x32x32_i8(aa0, bb2, acc02, 0, 0, 0);   \
    acc03 = __builtin_amdgcn_mfma_i32_32x32x32_i8(aa0, bb3, acc03, 0, 0, 0);   \
    acc10 = __builtin_amdgcn_mfma_i32_32x32x32_i8(aa1, bb0, acc10, 0, 0, 0);   \
    acc11 = __builtin_amdgcn_mfma_i32_32x32x32_i8(aa1, bb1, acc11, 0, 0, 0);   \
    acc12 = __builtin_amdgcn_mfma_i32_32x32x32_i8(aa1, bb2, acc12, 0, 0, 0);   \
    acc13 = __builtin_amdgcn_mfma_i32_32x32x32_i8(aa1, bb3, acc13, 0, 0, 0);

    v4i a0A, a1A, b0A, b1A, b2A, b3A;
    v4i a0B, a1B, b0B, b1B, b2B, b3B;

    LOADK(0, a0A, a1A, b0A, b1A, b2A, b3A)
    for (int kk = 0; kk < 72; kk += 2) {
        LOADK(kk + 1, a0B, a1B, b0B, b1B, b2B, b3B)
        MFMA8(a0A, a1A, b0A, b1A, b2A, b3A)
        if (kk + 2 < 72) {
            LOADK(kk + 2, a0A, a1A, b0A, b1A, b2A, b3A)
        }
        MFMA8(a0B, a1B, b0B, b1B, b2B, b3B)
    }
#undef LOADK
#undef MFMA8

    // ---- epilogue: 4 sub-tiles of 32 m-rows ----
#define EPIW(FM, F0, F1, F2, F3)                                               \
    {                                                                          \
        _Pragma("unroll")                                                      \
        for (int fn = 0; fn < 4; ++fn) {                                       \
            v16i fr = (fn == 0) ? F0 : (fn == 1) ? F1 : (fn == 2) ? F2 : F3;   \
            _Pragma("unroll")                                                  \
            for (int r = 0; r < 16; ++r) {                                     \
                int mloc = (r & 3) + 8 * (r >> 2) + 4 * lh;                    \
                float val = (float)fr[r] * inv_f[fn] + bias_f[fn];             \
                val = fminf(1.f, fmaxf(-1.f, val));                            \
                sE[mloc][wn * 128 + fn * 32 + l31] = val;                      \
            }                                                                  \
        }                                                                      \
    }

    #pragma unroll
    for (int msub = 0; msub < 4; ++msub) {
        __syncthreads();
        if (wm == (msub >> 1)) {
            if ((msub & 1) == 0) { EPIW(0, acc00, acc01, acc02, acc03) }
            else                 { EPIW(1, acc10, acc11, acc12, acc13) }
        }
        __syncthreads();
        // store phase: lane = m (coalesced), each thread covers 32 cos
        int mloc = t & 31;
        int cob  = (t >> 5) * 32;
        long gm  = bm0 + msub * 32 + mloc;
        int nimg = (int)(gm / (GP_ * GP_));
        int rem  = (int)(gm - (long)nimg * (GP_ * GP_));
        int yy = rem / GP_;
        int xx = rem - yy * GP_;
        if (yy < H_ && xx < W_) {
            size_t g = (((size_t)nimg * C_ + cob) * H_ + yy) * W_ + xx;
            #pragma unroll
            for (int k2 = 0; k2 < 32; ++k2) {
                out[g] = sE[mloc][cob + k2] + x[g];
                g += (size_t)(H_ * W_);
            }
        }
    }
#undef EPIW
}

// ===========================================================================
// Fallback path (round-3 popcount kernels, known-good) — used if ws too small
// ===========================================================================
__global__ __launch_bounds__(256) void pack_x_kernel(const float* __restrict__ x,
                                                     u64* __restrict__ xbits) {
    int nh = blockIdx.x;
    int h  = nh % H_;
    int n  = nh / H_;
    __shared__ float sx[C_][W_ + 1];
    const float* xplane = x + ((size_t)n * C_ * H_ + h) * W_;
    for (int i = threadIdx.x; i < C_ * 7; i += 256) {
        int c = i / 7, q = i - c * 7;
        float4 v = *(const float4*)(xplane + (size_t)c * (H_ * W_) + q * 4);
        sx[c][q*4+0]=v.x; sx[c][q*4+1]=v.y; sx[c][q*4+2]=v.z; sx[c][q*4+3]=v.w;
    }
    __syncthreads();
    int k    = threadIdx.x >> 6;
    int lane = threadIdx.x & 63;
    int c    = k * 64 + lane;
    u64 my = 0;
    #pragma unroll
    for (int w = 0; w < W_; ++w) {
        u64 mask = __ballot(sx[c][w] < 0.f);
        if (lane == w) my = mask;
    }
    if (lane < W_) xbits[((size_t)nh * W_ + lane) * 4 + k] = my;
}

__global__ __launch_bounds__(256) void pack_w_kernel(const float* __restrict__ w,
                                                     u64* __restrict__ wbits) {
    int gid  = blockIdx.x * blockDim.x + threadIdx.x;
    int wave = gid >> 6;
    int lane = gid & 63;
    if (wave >= C_ * 9 * 4) return;
    int k    = wave & 3;
    int rest = wave >> 2;
    int tap  = rest % 9;
    int co   = rest / 9;
    int ci   = k * 64 + lane;
    float val = w[((size_t)co * C_ + ci) * 9 + tap];
    u64 mask = __ballot(val < 0.f);
    if (lane == 0) wbits[wave] = mask;
}

__global__ __launch_bounds__(512, 4) void conv_kernel(
    const u64* __restrict__ xbits, const u64* __restrict__ wbits,
    const float* __restrict__ x,
    const float* __restrict__ gamma, const float* __restrict__ beta,
    const float* __restrict__ mean, const float* __restrict__ var,
    float* __restrict__ out) {
    int nh = blockIdx.x;
    int h  = nh % H_;
    int n  = nh / H_;
    int co = threadIdx.x >> 1;
    int kh = threadIdx.x & 1;

    __shared__ u64   lx[3][W_][4];
    __shared__ float sout[C_][W_ + 1];

    float inv  = gamma[co] / sqrtf(var[co] + BN_EPS_);
    float bias = beta[co] - mean[co] * inv;

    u64 wr[9][2];
    {
        const u64* wp = wbits + (size_t)co * 36 + kh * 2;
        #pragma unroll
        for (int t = 0; t < 9; ++t) {
            ulonglong2 a = *(const ulonglong2*)(wp + t * 4);
            wr[t][0] = a.x; wr[t][1] = a.y;
        }
    }
    if (threadIdx.x < 3 * W_ * 4) {
        int i    = threadIdx.x;
        int k    = i & 3;
        int rest = i >> 2;
        int ww   = rest % W_;
        int r    = rest / W_;
        int ih   = h - 1 + r;
        u64 v = 0;
        if (ih >= 0 && ih < H_)
            v = xbits[(((size_t)n * H_ + ih) * W_ + ww) * 4 + k];
        lx[r][ww][k] = v;
    }
    __syncthreads();

    const bool row0 = (h > 0);
    const bool row2 = (h < H_ - 1);
    const int  nrows = 1 + (row0 ? 1 : 0) + (row2 ? 1 : 0);
    const int  nv3 = C_ * nrows * 3;
    const int  nv2 = C_ * nrows * 2;

    int pm = 0, pc = 0;
    #pragma unroll 4
    for (int iw = 0; iw < W_; ++iw) {
        int a0 = 0, a1 = 0, a2 = 0;
        ulonglong2 xr;
        #define TAPROW(r, wb)                                                  \
            xr = *(const ulonglong2*)&lx[r][iw][kh * 2];                       \
            a0 += __popcll(xr.x ^ wr[wb+0][0]) + __popcll(xr.y ^ wr[wb+0][1]); \
            a1 += __popcll(xr.x ^ wr[wb+1][0]) + __popcll(xr.y ^ wr[wb+1][1]); \
            a2 += __popcll(xr.x ^ wr[wb+2][0]) + __popcll(xr.y ^ wr[wb+2][1]);
        if (row0) { TAPROW(0, 0) }
        { TAPROW(1, 3) }
        if (row2) { TAPROW(2, 6) }
        #undef TAPROW
        if (iw >= 1) {
            int s = pm + a2;
            s += __shfl_xor(s, 1);
            int nv = (iw == 1) ? nv2 : nv3;
            float val = (float)(nv - 2 * s) * inv + bias;
            val = fminf(1.f, fmaxf(-1.f, val));
            if (kh == 0) sout[co][iw - 1] = val;
        }
        pm = pc + a1;
        pc = a0;
    }
    {
        int s = pm;
        s += __shfl_xor(s, 1);
        float val = (float)(nv2 - 2 * s) * inv + bias;
        val = fminf(1.f, fmaxf(-1.f, val));
        if (kh == 0) sout[co][W_ - 1] = val;
    }
    __syncthreads();

    const float* xplane = x   + ((size_t)n * C_ * H_ + h) * W_;
    float*       oplane = out + ((size_t)n * C_ * H_ + h) * W_;
    for (int i = threadIdx.x; i < C_ * 7; i += 512) {
        int c = i / 7, q = i - c * 7;
        size_t g = (size_t)c * (H_ * W_) + q * 4;
        float4 r = *(const float4*)(xplane + g);
        float4 o;
        o.x = sout[c][q*4+0] + r.x;
        o.y = sout[c][q*4+1] + r.y;
        o.z = sout[c][q*4+2] + r.z;
        o.w = sout[c][q*4+3] + r.w;
        *(float4*)(oplane + g) = o;
    }
}

// ---------------------------------------------------------------------------
extern "C" void kernel_launch(void* const* d_in, const int* in_sizes, int n_in,
                              void* d_out, int out_size, void* d_ws, size_t ws_size,
                              hipStream_t stream) {
    const float* x     = (const float*)d_in[0];
    const float* w     = (const float*)d_in[1];
    const float* gamma = (const float*)d_in[2];
    const float* beta  = (const float*)d_in[3];
    const float* mean  = (const float*)d_in[4];
    const float* var   = (const float*)d_in[5];
    float* out = (float*)d_out;

    if (ws_size >= A_BYTES_ + B_BYTES_) {
        char* Abuf = (char*)d_ws;
        char* Bbuf = Abuf + A_BYTES_;
        pack_a_kernel<<<N_ * GP_, 256, 0, stream>>>(x, Abuf);
        pack_b_kernel<<<9 * 8, 256, 0, stream>>>(w, Bbuf);
        gemm_kernel<<<MROWS_ / 128, 256, 0, stream>>>(Abuf, Bbuf, x, gamma, beta,
                                                      mean, var, out);
    } else {
        u64* xbits = (u64*)d_ws;
        u64* wbits = xbits + (size_t)N_ * H_ * W_ * 4;
        pack_x_kernel<<<N_ * H_, 256, 0, stream>>>(x, xbits);
        pack_w_kernel<<<(C_ * 9 * 4 * 64) / 256, 256, 0, stream>>>(w, wbits);
        conv_kernel<<<N_ * H_, 512, 0, stream>>>(xbits, wbits, x, gamma, beta,
                                                 mean, var, out);
    }
}

// Round 6
// 332.614 us; speedup vs baseline: 1.3172x; 1.3172x over previous
//
#include <hip/hip_runtime.h>
#include <stdint.h>

typedef unsigned long long u64;
typedef int v4i  __attribute__((ext_vector_type(4)));
typedef int v16i __attribute__((ext_vector_type(16)));

#define N_ 128
#define C_ 256
#define H_ 28
#define W_ 28
#define BN_EPS_ 1e-5f

#define GP_ 30                            // zero-padded grid 30x30
#define MROWS_ (N_ * GP_ * GP_)           // 115200 GEMM rows
#define A_BYTES_ ((size_t)(MROWS_ + 64) * C_)   // + rear slack (shift reads <= +62 rows)
#define B_BYTES_ ((size_t)9 * C_ * C_)

static __device__ inline v16i vzero16() {
    v16i v;
    #pragma unroll
    for (int i = 0; i < 16; ++i) v[i] = 0;
    return v;
}

static __device__ inline void gll16(const void* g, void* l) {
    __builtin_amdgcn_global_load_lds(
        (const __attribute__((address_space(1))) void*)g,
        (__attribute__((address_space(3))) void*)l, 16, 0, 0);
}

// ===========================================================================
// MFMA path
// ===========================================================================

// ---------------------------------------------------------------------------
// pack_a: A[n][gy][gx][ci] i8 = sign(x[n,ci,gy-1,gx-1]) in {+1,-1}, zero halo.
// Stage TRANSPOSED sxt[w][c] so the emit phase reads one float4 per dword
// (ds_read_b128, lane-consecutive = conflict-free) instead of 4 strided
// scalar LDS reads.
// ---------------------------------------------------------------------------
__global__ __launch_bounds__(256) void pack_a_kernel(const float* __restrict__ x,
                                                     char* __restrict__ A) {
    int gy = blockIdx.x % GP_;
    int n  = blockIdx.x / GP_;
    int* arow = (int*)(A + ((size_t)n * GP_ + gy) * GP_ * C_);
    if (gy == 0 || gy == GP_ - 1) {
        for (int i = threadIdx.x; i < GP_ * 64; i += 256) arow[i] = 0;
        return;
    }
    int h = gy - 1;
    __shared__ float sxt[W_][C_ + 4];   // [w][c], 28*260*4 = 29120 B
    const float* xplane = x + ((size_t)n * C_ * H_ + h) * W_;
    for (int i = threadIdx.x; i < C_ * 7; i += 256) {
        int c = i / 7, q = i - c * 7;
        float4 v = *(const float4*)(xplane + (size_t)c * (H_ * W_) + q * 4);
        sxt[q * 4 + 0][c] = v.x;
        sxt[q * 4 + 1][c] = v.y;
        sxt[q * 4 + 2][c] = v.z;
        sxt[q * 4 + 3][c] = v.w;
    }
    __syncthreads();
    for (int i = threadIdx.x; i < GP_ * 64; i += 256) {
        int gx = i >> 6, d = i & 63;
        unsigned r = 0;
        if (gx > 0 && gx < GP_ - 1) {
            float4 v = *(const float4*)&sxt[gx - 1][4 * d];
            unsigned b0 = v.x < 0.f ? 0xFFu : 0x01u;
            unsigned b1 = v.y < 0.f ? 0xFFu : 0x01u;
            unsigned b2 = v.z < 0.f ? 0xFFu : 0x01u;
            unsigned b3 = v.w < 0.f ? 0xFFu : 0x01u;
            r = b0 | (b1 << 8) | (b2 << 16) | (b3 << 24);
        }
        arow[i] = (int)r;
    }
}

// ---------------------------------------------------------------------------
// pack_b: B[tap][co][ci] i8 = sign(w[co,ci,tap]), tap = kh*3+kw.
// ---------------------------------------------------------------------------
__global__ __launch_bounds__(256) void pack_b_kernel(const float* __restrict__ w,
                                                     char* __restrict__ B) {
    int tap = blockIdx.x % 9;
    int cog = blockIdx.x / 9;
    int co  = cog * 32 + (threadIdx.x >> 3);
    int* brow = (int*)(B + ((size_t)tap * C_ + co) * C_);
    for (int k = 0; k < 8; ++k) {
        int d = (threadIdx.x & 7) + 8 * k;
        unsigned r = 0;
        #pragma unroll
        for (int j = 0; j < 4; ++j) {
            int ci = 4 * d + j;
            float v = w[((size_t)co * C_ + ci) * 9 + tap];
            r |= (v < 0.f ? 0xFFu : 0x01u) << (8 * j);
        }
        brow[d] = (int)r;
    }
}

// ---------------------------------------------------------------------------
// gemm: LDS-staged, double-buffered i8 MFMA GEMM (m97-style 2-phase).
// Block = 128 m x 128 co, K-step 64 (36 steps = 9 taps x 4). 4 waves,
// wave-tile 64x64, frags 2m x 2n of mfma_i32_32x32x32_i8.
// Staging: global_load_lds width-16, LDS linear, SOURCE pre-swizzled
// (slot ^= row&3) and the same XOR applied on ds_read -> 8 words/bank
// (conflict-free). A row shift per tap = dh*30+dw handled in source addr.
// ---------------------------------------------------------------------------
__global__ __launch_bounds__(256, 3) void gemm_kernel(
    const char* __restrict__ A, const char* __restrict__ B,
    const float* __restrict__ x,
    const float* __restrict__ gamma, const float* __restrict__ beta,
    const float* __restrict__ mean, const float* __restrict__ var,
    float* __restrict__ out) {

    int t    = threadIdx.x;
    int wid  = t >> 6, lane = t & 63;
    int wm   = wid & 1, wn = wid >> 1;      // wave grid 2m x 2n
    int l31  = lane & 31, lh = lane >> 5;
    int bm0  = blockIdx.x * 128;
    int bn0  = blockIdx.y * 128;

    __shared__ union __align__(16) {
        struct { char A[2][8192]; char Bp[2][8192]; } kb;   // 32768 B
        float sE[32][129];                                  // 16512 B
    } sm;

    int wv = __builtin_amdgcn_readfirstlane(wid);

    // BN params: co = bn0 + wn*64 + fn*32 + l31
    float inv_f[2], bias_f[2];
    #pragma unroll
    for (int fn = 0; fn < 2; ++fn) {
        int co = bn0 + wn * 64 + fn * 32 + l31;
        float iv = gamma[co] / sqrtf(var[co] + BN_EPS_);
        inv_f[fn]  = iv;
        bias_f[fn] = beta[co] - mean[co] * iv;
    }

    // ---- staging geometry (per-lane, constant across steps) ----
    int srow  = lane >> 2;                 // 0..15 row within 16-row chunk
    int xslot = (lane & 3) ^ (srow & 3);   // pre-swizzled source slot
    // A: wave wv stages rows wv*32 .. wv*32+32 (2 chunks of 16 rows)
    const char* srcA0 = A + (size_t)(bm0 + wv * 32 + srow) * C_ + xslot * 16;
    const char* srcA1 = srcA0 + 16 * C_;
    const char* srcB0 = B + (size_t)(bn0 + wv * 32 + srow) * C_ + xslot * 16;
    const char* srcB1 = srcB0 + 16 * C_;

    v16i acc00 = vzero16(), acc01 = vzero16();
    v16i acc10 = vzero16(), acc11 = vzero16();

    // ds_read swizzled slot offsets (row&3 == l31&3 for all frag rows)
    int rx4 = l31 & 3;
    int sl0 = ((lh)     ^ rx4) * 16;   // kc=0: slot = lh
    int sl1 = ((2 | lh) ^ rx4) * 16;   // kc=1: slot = 2+lh
    int arow0 = (wm * 64 + l31) * 64, arow1 = arow0 + 32 * 64;
    int brow0 = (wn * 64 + l31) * 64, brow1 = brow0 + 32 * 64;

    auto stage = [&](int buf, int step) {
        int tap = step >> 2, sub = step & 3;
        int dh = tap / 3, dw = tap - dh * 3;
        size_t ao = (size_t)(dh * GP_ + dw) * C_ + (size_t)sub * 64;
        size_t bo = (size_t)tap * (C_ * C_) + (size_t)sub * 64;
        char* dA = sm.kb.A[buf]  + wv * 2048;
        char* dB = sm.kb.Bp[buf] + wv * 2048;
        gll16(srcA0 + ao, dA);
        gll16(srcA1 + ao, dA + 1024);
        gll16(srcB0 + bo, dB);
        gll16(srcB1 + bo, dB + 1024);
    };

    auto compute = [&](int buf) {
        const char* lA = sm.kb.A[buf];
        const char* lB = sm.kb.Bp[buf];
        v4i a00 = *(const v4i*)(lA + arow0 + sl0);
        v4i a01 = *(const v4i*)(lA + arow0 + sl1);
        v4i a10 = *(const v4i*)(lA + arow1 + sl0);
        v4i a11 = *(const v4i*)(lA + arow1 + sl1);
        v4i b00 = *(const v4i*)(lB + brow0 + sl0);
        v4i b01 = *(const v4i*)(lB + brow0 + sl1);
        v4i b10 = *(const v4i*)(lB + brow1 + sl0);
        v4i b11 = *(const v4i*)(lB + brow1 + sl1);
        acc00 = __builtin_amdgcn_mfma_i32_32x32x32_i8(a00, b00, acc00, 0, 0, 0);
        acc01 = __builtin_amdgcn_mfma_i32_32x32x32_i8(a00, b10, acc01, 0, 0, 0);
        acc10 = __builtin_amdgcn_mfma_i32_32x32x32_i8(a10, b00, acc10, 0, 0, 0);
        acc11 = __builtin_amdgcn_mfma_i32_32x32x32_i8(a10, b10, acc11, 0, 0, 0);
        acc00 = __builtin_amdgcn_mfma_i32_32x32x32_i8(a01, b01, acc00, 0, 0, 0);
        acc01 = __builtin_amdgcn_mfma_i32_32x32x32_i8(a01, b11, acc01, 0, 0, 0);
        acc10 = __builtin_amdgcn_mfma_i32_32x32x32_i8(a11, b01, acc10, 0, 0, 0);
        acc11 = __builtin_amdgcn_mfma_i32_32x32x32_i8(a11, b11, acc11, 0, 0, 0);
    };

    // ---- 2-phase double-buffered K loop (compile-time buffer indices) ----
    stage(0, 0);
    __syncthreads();
    for (int s = 0; s < 36; s += 2) {
        stage(1, s + 1);            // s+1 <= 35 always (36 even)
        compute(0);
        __syncthreads();
        if (s + 2 < 36) stage(0, s + 2);
        compute(1);
        __syncthreads();
    }

    // ---- epilogue: 4 sub-tiles of 32 m-rows (mapping verified round 5) ----
    #pragma unroll
    for (int msub = 0; msub < 4; ++msub) {
        if (wm == (msub >> 1)) {
            #pragma unroll
            for (int fn = 0; fn < 2; ++fn) {
                v16i fr;
                if ((msub & 1) == 0) fr = (fn == 0) ? acc00 : acc01;
                else                 fr = (fn == 0) ? acc10 : acc11;
                #pragma unroll
                for (int r = 0; r < 16; ++r) {
                    int mloc = (r & 3) + 8 * (r >> 2) + 4 * lh;
                    float val = (float)fr[r] * inv_f[fn] + bias_f[fn];
                    val = fminf(1.f, fmaxf(-1.f, val));
                    sm.sE[mloc][wn * 64 + fn * 32 + l31] = val;
                }
            }
        }
        __syncthreads();
        // store: lane = m (coalesced); each thread covers 16 cos
        int mloc = t & 31;
        int cog  = t >> 5;                     // 0..7 -> 16 cos each
        int gm   = bm0 + msub * 32 + mloc;
        int nimg = gm / (GP_ * GP_);
        int rem  = gm - nimg * (GP_ * GP_);
        int yy = rem / GP_;
        int xx = rem - yy * GP_;
        if (yy < H_ && xx < W_) {
            size_t g = (((size_t)nimg * C_ + bn0 + cog * 16) * H_ + yy) * W_ + xx;
            #pragma unroll
            for (int k2 = 0; k2 < 16; ++k2) {
                out[g] = sm.sE[mloc][cog * 16 + k2] + x[g];
                g += (size_t)(H_ * W_);
            }
        }
        __syncthreads();
    }
}

// ===========================================================================
// Fallback path (round-3 popcount kernels, known-good) — used if ws too small
// ===========================================================================
__global__ __launch_bounds__(256) void pack_x_kernel(const float* __restrict__ x,
                                                     u64* __restrict__ xbits) {
    int nh = blockIdx.x;
    int h  = nh % H_;
    int n  = nh / H_;
    __shared__ float sx[C_][W_ + 1];
    const float* xplane = x + ((size_t)n * C_ * H_ + h) * W_;
    for (int i = threadIdx.x; i < C_ * 7; i += 256) {
        int c = i / 7, q = i - c * 7;
        float4 v = *(const float4*)(xplane + (size_t)c * (H_ * W_) + q * 4);
        sx[c][q*4+0]=v.x; sx[c][q*4+1]=v.y; sx[c][q*4+2]=v.z; sx[c][q*4+3]=v.w;
    }
    __syncthreads();
    int k    = threadIdx.x >> 6;
    int lane = threadIdx.x & 63;
    int c    = k * 64 + lane;
    u64 my = 0;
    #pragma unroll
    for (int w = 0; w < W_; ++w) {
        u64 mask = __ballot(sx[c][w] < 0.f);
        if (lane == w) my = mask;
    }
    if (lane < W_) xbits[((size_t)nh * W_ + lane) * 4 + k] = my;
}

__global__ __launch_bounds__(256) void pack_w_kernel(const float* __restrict__ w,
                                                     u64* __restrict__ wbits) {
    int gid  = blockIdx.x * blockDim.x + threadIdx.x;
    int wave = gid >> 6;
    int lane = gid & 63;
    if (wave >= C_ * 9 * 4) return;
    int k    = wave & 3;
    int rest = wave >> 2;
    int tap  = rest % 9;
    int co   = rest / 9;
    int ci   = k * 64 + lane;
    float val = w[((size_t)co * C_ + ci) * 9 + tap];
    u64 mask = __ballot(val < 0.f);
    if (lane == 0) wbits[wave] = mask;
}

__global__ __launch_bounds__(512, 4) void conv_kernel(
    const u64* __restrict__ xbits, const u64* __restrict__ wbits,
    const float* __restrict__ x,
    const float* __restrict__ gamma, const float* __restrict__ beta,
    const float* __restrict__ mean, const float* __restrict__ var,
    float* __restrict__ out) {
    int nh = blockIdx.x;
    int h  = nh % H_;
    int n  = nh / H_;
    int co = threadIdx.x >> 1;
    int kh = threadIdx.x & 1;

    __shared__ u64   lx[3][W_][4];
    __shared__ float sout[C_][W_ + 1];

    float inv  = gamma[co] / sqrtf(var[co] + BN_EPS_);
    float bias = beta[co] - mean[co] * inv;

    u64 wr[9][2];
    {
        const u64* wp = wbits + (size_t)co * 36 + kh * 2;
        #pragma unroll
        for (int tt = 0; tt < 9; ++tt) {
            ulonglong2 a = *(const ulonglong2*)(wp + tt * 4);
            wr[tt][0] = a.x; wr[tt][1] = a.y;
        }
    }
    if (threadIdx.x < 3 * W_ * 4) {
        int i    = threadIdx.x;
        int k    = i & 3;
        int rest = i >> 2;
        int ww   = rest % W_;
        int r    = rest / W_;
        int ih   = h - 1 + r;
        u64 v = 0;
        if (ih >= 0 && ih < H_)
            v = xbits[(((size_t)n * H_ + ih) * W_ + ww) * 4 + k];
        lx[r][ww][k] = v;
    }
    __syncthreads();

    const bool row0 = (h > 0);
    const bool row2 = (h < H_ - 1);
    const int  nrows = 1 + (row0 ? 1 : 0) + (row2 ? 1 : 0);
    const int  nv3 = C_ * nrows * 3;
    const int  nv2 = C_ * nrows * 2;

    int pm = 0, pc = 0;
    #pragma unroll 4
    for (int iw = 0; iw < W_; ++iw) {
        int a0 = 0, a1 = 0, a2 = 0;
        ulonglong2 xr;
        #define TAPROW(r, wb)                                                  \
            xr = *(const ulonglong2*)&lx[r][iw][kh * 2];                       \
            a0 += __popcll(xr.x ^ wr[wb+0][0]) + __popcll(xr.y ^ wr[wb+0][1]); \
            a1 += __popcll(xr.x ^ wr[wb+1][0]) + __popcll(xr.y ^ wr[wb+1][1]); \
            a2 += __popcll(xr.x ^ wr[wb+2][0]) + __popcll(xr.y ^ wr[wb+2][1]);
        if (row0) { TAPROW(0, 0) }
        { TAPROW(1, 3) }
        if (row2) { TAPROW(2, 6) }
        #undef TAPROW
        if (iw >= 1) {
            int s = pm + a2;
            s += __shfl_xor(s, 1);
            int nv = (iw == 1) ? nv2 : nv3;
            float val = (float)(nv - 2 * s) * inv + bias;
            val = fminf(1.f, fmaxf(-1.f, val));
            if (kh == 0) sout[co][iw - 1] = val;
        }
        pm = pc + a1;
        pc = a0;
    }
    {
        int s = pm;
        s += __shfl_xor(s, 1);
        float val = (float)(nv2 - 2 * s) * inv + bias;
        val = fminf(1.f, fmaxf(-1.f, val));
        if (kh == 0) sout[co][W_ - 1] = val;
    }
    __syncthreads();

    const float* xplane = x   + ((size_t)n * C_ * H_ + h) * W_;
    float*       oplane = out + ((size_t)n * C_ * H_ + h) * W_;
    for (int i = threadIdx.x; i < C_ * 7; i += 512) {
        int c = i / 7, q = i - c * 7;
        size_t g = (size_t)c * (H_ * W_) + q * 4;
        float4 r = *(const float4*)(xplane + g);
        float4 o;
        o.x = sout[c][q*4+0] + r.x;
        o.y = sout[c][q*4+1] + r.y;
        o.z = sout[c][q*4+2] + r.z;
        o.w = sout[c][q*4+3] + r.w;
        *(float4*)(oplane + g) = o;
    }
}

// ---------------------------------------------------------------------------
extern "C" void kernel_launch(void* const* d_in, const int* in_sizes, int n_in,
                              void* d_out, int out_size, void* d_ws, size_t ws_size,
                              hipStream_t stream) {
    const float* x     = (const float*)d_in[0];
    const float* w     = (const float*)d_in[1];
    const float* gamma = (const float*)d_in[2];
    const float* beta  = (const float*)d_in[3];
    const float* mean  = (const float*)d_in[4];
    const float* var   = (const float*)d_in[5];
    float* out = (float*)d_out;

    if (ws_size >= A_BYTES_ + B_BYTES_) {
        char* Abuf = (char*)d_ws;
        char* Bbuf = Abuf + A_BYTES_;
        pack_a_kernel<<<N_ * GP_, 256, 0, stream>>>(x, Abuf);
        pack_b_kernel<<<9 * 8, 256, 0, stream>>>(w, Bbuf);
        gemm_kernel<<<dim3(MROWS_ / 128, 2), 256, 0, stream>>>(Abuf, Bbuf, x, gamma,
                                                               beta, mean, var, out);
    } else {
        u64* xbits = (u64*)d_ws;
        u64* wbits = xbits + (size_t)N_ * H_ * W_ * 4;
        pack_x_kernel<<<N_ * H_, 256, 0, stream>>>(x, xbits);
        pack_w_kernel<<<(C_ * 9 * 4 * 64) / 256, 256, 0, stream>>>(w, wbits);
        conv_kernel<<<N_ * H_, 512, 0, stream>>>(xbits, wbits, x, gamma, beta,
                                                 mean, var, out);
    }
}